// Round 9
// baseline (64.525 us; speedup 1.0000x reference)
//
#include <hip/hip_runtime.h>
#include <hip/hip_bf16.h>
#include <cstdint>

typedef __bf16 bf16_t;
typedef __bf16 bf16x8 __attribute__((ext_vector_type(8)));
typedef float f32x4 __attribute__((ext_vector_type(4)));

#define B_ 4
#define S_ 4096
#define E_ 1024
#define L_ 64

__device__ __forceinline__ f32x4 mfma16(bf16x8 a, bf16x8 b, f32x4 c) {
  return __builtin_amdgcn_mfma_f32_16x16x32_bf16(a, b, c, 0, 0, 0);
}

// DPP rotate-reduce within 16-lane rows (VALU, no LDS traffic).
template <int CTRL>
__device__ __forceinline__ float dpp_max_step(float x) {
  int t = __builtin_amdgcn_update_dpp(0, __float_as_int(x), CTRL, 0xF, 0xF, true);
  return fmaxf(x, __int_as_float(t));
}
template <int CTRL>
__device__ __forceinline__ float dpp_add_step(float x) {
  int t = __builtin_amdgcn_update_dpp(0, __float_as_int(x), CTRL, 0xF, 0xF, true);
  return x + __int_as_float(t);
}
__device__ __forceinline__ float dpp_reduce_max16(float x) {
  x = dpp_max_step<0x121>(x);
  x = dpp_max_step<0x122>(x);
  x = dpp_max_step<0x124>(x);
  x = dpp_max_step<0x128>(x);
  return x;
}
__device__ __forceinline__ float dpp_reduce_add16(float x) {
  x = dpp_add_step<0x121>(x);
  x = dpp_add_step<0x122>(x);
  x = dpp_add_step<0x124>(x);
  x = dpp_add_step<0x128>(x);
  return x;
}

// Fragment-tile layout: tile = (16 rows x 32 k); flat ((tile)*64 + lane)*8,
// lane = lg*16+lr holds M[t_row*16+lr][t_k*32+lg*8..+8]. Wave fragment load =
// base + l*16B -> one coalesced 1KB access.

// ---- kernel 1: W [E][64] -> Wf fragment tiles (nt 0..11, kt 0..31) ----
__global__ void prep_w_kernel(const float* __restrict__ Wq, const float* __restrict__ Wk,
                              const float* __restrict__ Wv, bf16_t* __restrict__ Wf) {
  int n = blockIdx.x;  // 0..191 output col (W^T row)
  const float* W = (n < 64) ? Wq : (n < 128 ? Wk : Wv);
  int col = n & 63;
  int nt = n >> 4, lr = n & 15;
  for (int k = threadIdx.x; k < E_; k += blockDim.x) {
    int kt = k >> 5, lg = (k >> 3) & 3, e = k & 7;
    Wf[((size_t)((nt * 32 + kt) * 64 + lg * 16 + lr) << 3) + e] = (bf16_t)W[(size_t)k * L_ + col];
  }
}

// ---- kernel 2: QKV projection v3. Block = 64 rows x 192 cols; whole x-slice
// staged ONCE into 129KB LDS (one barrier), then barrier-free compute streaming
// Wf from L2 with 2x3 register blocking. Epilogue: C->LDS->fragment stores. ----
__global__ __launch_bounds__(512) void qkv_proj_kernel(
    const float* __restrict__ x, const bf16_t* __restrict__ Wf,
    const float* __restrict__ bq, const float* __restrict__ bk, const float* __restrict__ bv,
    bf16_t* __restrict__ Qf, bf16_t* __restrict__ Kf, bf16_t* __restrict__ Vf) {
  __shared__ __align__(16) char smem[64 * 1032 * 2];   // 129 KiB
  bf16_t* xls = reinterpret_cast<bf16_t*>(smem);       // [64][1032] (pad 8 -> bank-safe)
  bf16_t* stc = reinterpret_cast<bf16_t*>(smem);       // epilogue alias: [64][200]

  const int tid = threadIdx.x;
  const int w = tid >> 6, l = tid & 63;
  const int lr = l & 15, lg = l >> 4;
  const int wr = w & 1, wc = w >> 1;  // 2 row-groups x 4 col-groups
  const int m0 = blockIdx.x * 64;

  // ---- stage x[m0..+64][0..1024] -> LDS bf16 (coalesced 512B/row segments) ----
  {
    const int srow = tid >> 3, sc8 = tid & 7;
    const float* src = x + (size_t)(m0 + srow) * E_;
    bf16_t* dst = xls + srow * 1032;
#pragma unroll
    for (int i = 0; i < 8; ++i) {
      const int c0 = sc8 * 16 + i * 128;
      float4 u0 = *reinterpret_cast<const float4*>(src + c0);
      float4 u1 = *reinterpret_cast<const float4*>(src + c0 + 4);
      float4 u2 = *reinterpret_cast<const float4*>(src + c0 + 8);
      float4 u3 = *reinterpret_cast<const float4*>(src + c0 + 12);
      bf16x8 p0, p1;
      p0[0] = (bf16_t)u0.x; p0[1] = (bf16_t)u0.y; p0[2] = (bf16_t)u0.z; p0[3] = (bf16_t)u0.w;
      p0[4] = (bf16_t)u1.x; p0[5] = (bf16_t)u1.y; p0[6] = (bf16_t)u1.z; p0[7] = (bf16_t)u1.w;
      p1[0] = (bf16_t)u2.x; p1[1] = (bf16_t)u2.y; p1[2] = (bf16_t)u2.z; p1[3] = (bf16_t)u2.w;
      p1[4] = (bf16_t)u3.x; p1[5] = (bf16_t)u3.y; p1[6] = (bf16_t)u3.z; p1[7] = (bf16_t)u3.w;
      *reinterpret_cast<bf16x8*>(dst + c0) = p0;
      *reinterpret_cast<bf16x8*>(dst + c0 + 8) = p1;
    }
  }
  __syncthreads();

  // ---- compute: wave = rows [wr*32, +32) x cols [wc*48, +48); acc 2x3 ----
  f32x4 acc[2][3];
#pragma unroll
  for (int at = 0; at < 2; ++at)
#pragma unroll
    for (int t = 0; t < 3; ++t) acc[at][t] = f32x4{0.f, 0.f, 0.f, 0.f};

  const bf16_t* xa0 = xls + (size_t)(wr * 32 + lr) * 1032 + lg * 8;
  const bf16_t* xa1 = xa0 + (size_t)16 * 1032;
#pragma unroll 4
  for (int kt = 0; kt < 32; ++kt) {
    bf16x8 a0 = *reinterpret_cast<const bf16x8*>(xa0 + kt * 32);
    bf16x8 a1 = *reinterpret_cast<const bf16x8*>(xa1 + kt * 32);
#pragma unroll
    for (int t = 0; t < 3; ++t) {
      const int nt = wc * 3 + t;
      bf16x8 b = *reinterpret_cast<const bf16x8*>(Wf + (((size_t)(nt * 32 + kt) * 64 + l) << 3));
      acc[0][t] = mfma16(a0, b, acc[0][t]);
      acc[1][t] = mfma16(a1, b, acc[1][t]);
    }
  }
  __syncthreads();  // all xls reads retired; smem reused as stc

  // ---- C (+bias) -> stc[64][200] bf16 ----
#pragma unroll
  for (int t = 0; t < 3; ++t) {
    const int colb = wc * 48 + t * 16;  // 16-tile never straddles a matrix
    const int col = colb + lr;
    const int mat = colb >> 6;
    const float* bias = (mat == 0) ? bq : (mat == 1 ? bk : bv);
    const float bb = bias[col & 63];
#pragma unroll
    for (int at = 0; at < 2; ++at)
#pragma unroll
      for (int r = 0; r < 4; ++r) {
        const int row = wr * 32 + at * 16 + lg * 4 + r;
        stc[row * 200 + col] = (bf16_t)(acc[at][t][r] + bb);
      }
  }
  __syncthreads();

  // ---- fragment-layout coalesced 16B global stores ----
  {
    // Q and K: thread -> (rt 0..3, ktq 0..1, lane 0..63)
    const int rt = tid >> 7, ktq = (tid >> 6) & 1, lane = tid & 63;
    const int lgw = lane >> 4, lrw = lane & 15;
    const int rtg = (m0 >> 4) + rt;
    bf16x8 qv = *reinterpret_cast<const bf16x8*>(stc + (rt * 16 + lrw) * 200 + ktq * 32 + lgw * 8);
    *reinterpret_cast<bf16x8*>(Qf + (((size_t)(rtg * 2 + ktq) * 64 + lane) << 3)) = qv;
    bf16x8 kv = *reinterpret_cast<const bf16x8*>(stc + (rt * 16 + lrw) * 200 + 64 + ktq * 32 + lgw * 8);
    *reinterpret_cast<bf16x8*>(Kf + (((size_t)(rtg * 2 + ktq) * 64 + lane) << 3)) = kv;
    // V: thread -> (stl 0..1, vt 0..3, lane 0..63); elements = 8 consecutive rows
    const int stl = tid >> 8, vt = (tid >> 6) & 3;
    const int lgv = lane >> 4, lrv = lane & 15;
    const int colv = vt * 16 + lrv;
    bf16x8 vv;
#pragma unroll
    for (int e = 0; e < 8; ++e)
      vv[e] = stc[(stl * 32 + lgv * 8 + e) * 200 + 128 + colv];
    const int batch = m0 >> 12;
    const int stg = ((m0 & (S_ - 1)) >> 5) + stl;
    *reinterpret_cast<bf16x8*>(Vf + ((size_t)batch << 18) + (((size_t)(stg * 4 + vt) * 64 + lane) << 3)) = vv;
  }
}

// ---- kernel 3: causal flash attention, split-K x8 (unchanged from R7/R8). ----
__global__ __launch_bounds__(256) void attn_kernel(
    const bf16_t* __restrict__ Qf, const bf16_t* __restrict__ Kf,
    const bf16_t* __restrict__ Vf, float* __restrict__ Opart, float* __restrict__ mlpart) {
  __shared__ __align__(16) bf16_t p_lds[4][16 * 72];  // 9 KiB P staging
  __shared__ bf16_t od_lds[3][16][68];                 // 6.4 KiB partial O (bf16)
  __shared__ float ml_lds[3][16][2];

  const int c = threadIdx.x >> 6, l = threadIdx.x & 63;
  const int lr = l & 15, lg = l >> 4;
  const int u = blockIdx.x;
  const int batch = u & 3;
  const int strip = (u >> 2) & 3;
  const int h = (u >> 4) & 1;
  const int qt = 63 - (u >> 5);
  const int qsi = ((u >> 5) << 4) | (u & 15);  // 0..1023 q-strip id
  const int qrow = qt * 64 + strip * 16;       // batch-local
  const size_t qbase = (size_t)batch * S_ + qrow;
  bf16_t* pw = p_lds[c];

  const int rtq = batch * 256 + qt * 4 + strip;  // global 16-row tile of Q
  bf16x8 qa0 = *reinterpret_cast<const bf16x8*>(Qf + (((size_t)(rtq * 2) * 64 + l) << 3));
  bf16x8 qa1 = *reinterpret_cast<const bf16x8*>(Qf + (((size_t)(rtq * 2 + 1) * 64 + l) << 3));
  const bf16_t* Vb = Vf + ((size_t)batch << 18);

  f32x4 o[4];
  float m[4], ssum[4];
#pragma unroll
  for (int rr = 0; rr < 4; ++rr) { o[rr] = f32x4{0.f, 0.f, 0.f, 0.f}; m[rr] = -1e30f; ssum[rr] = 0.f; }

  for (int kt = 2 * c + h; kt <= qt; kt += 8) {
    const int t0 = kt * 64;
    f32x4 st[4];
#pragma unroll
    for (int cf = 0; cf < 4; ++cf) st[cf] = f32x4{0.f, 0.f, 0.f, 0.f};
#pragma unroll
    for (int cf = 0; cf < 4; ++cf) {
      const int rtk = batch * 256 + kt * 4 + cf;
      bf16x8 b0 = *reinterpret_cast<const bf16x8*>(Kf + (((size_t)(rtk * 2) * 64 + l) << 3));
      bf16x8 b1 = *reinterpret_cast<const bf16x8*>(Kf + (((size_t)(rtk * 2 + 1) * 64 + l) << 3));
      st[cf] = mfma16(qa0, b0, st[cf]);
      st[cf] = mfma16(qa1, b1, st[cf]);
    }
    const bool diag = (kt == qt);
    float p[4][4];  // [cf][reg]
#pragma unroll
    for (int rr = 0; rr < 4; ++rr) {
      const int qg = qrow + lg * 4 + rr;
      float rowmax = -1e30f;
#pragma unroll
      for (int cf = 0; cf < 4; ++cf) {
        float s = st[cf][rr] * 0.125f;  // 1/sqrt(64)
        if (diag && (t0 + cf * 16 + lr) > qg) s = -1e30f;
        p[cf][rr] = s;
        rowmax = fmaxf(rowmax, s);
      }
      rowmax = dpp_reduce_max16(rowmax);
      float mnew = fmaxf(m[rr], rowmax);
      float scale = __expf(m[rr] - mnew);
      float rs = 0.f;
#pragma unroll
      for (int cf = 0; cf < 4; ++cf) {
        float e = __expf(p[cf][rr] - mnew);
        p[cf][rr] = e;
        rs += e;
      }
      rs = dpp_reduce_add16(rs);
      ssum[rr] = ssum[rr] * scale + rs;
#pragma unroll
      for (int cf = 0; cf < 4; ++cf) o[cf][rr] *= scale;
      m[rr] = mnew;
    }
    // P (C-layout) -> LDS -> A-layout fragments (wave-private, no barrier)
#pragma unroll
    for (int rr = 0; rr < 4; ++rr)
#pragma unroll
      for (int cf = 0; cf < 4; ++cf)
        pw[(lg * 4 + rr) * 72 + cf * 16 + lr] = (bf16_t)p[cf][rr];
    bf16x8 pa0 = *reinterpret_cast<const bf16x8*>(pw + lr * 72 + lg * 8);
    bf16x8 pa1 = *reinterpret_cast<const bf16x8*>(pw + lr * 72 + 32 + lg * 8);
    const int st0 = kt * 2;
#pragma unroll
    for (int cf = 0; cf < 4; ++cf) {
      bf16x8 v0 = *reinterpret_cast<const bf16x8*>(Vb + (((size_t)((st0 * 4 + cf) * 64 + l)) << 3));
      bf16x8 v1 = *reinterpret_cast<const bf16x8*>(Vb + (((size_t)(((st0 + 1) * 4 + cf) * 64 + l)) << 3));
      o[cf] = mfma16(pa0, v0, o[cf]);
      o[cf] = mfma16(pa1, v1, o[cf]);
    }
  }

  // chunks c=1..3 export to LDS; c=0 merges, writes unnormalized partial.
  if (c > 0) {
    if (lr == 0) {
#pragma unroll
      for (int rr = 0; rr < 4; ++rr) {
        ml_lds[c - 1][lg * 4 + rr][0] = m[rr];
        ml_lds[c - 1][lg * 4 + rr][1] = ssum[rr];
      }
    }
#pragma unroll
    for (int cf = 0; cf < 4; ++cf)
#pragma unroll
      for (int rr = 0; rr < 4; ++rr)
        od_lds[c - 1][lg * 4 + rr][cf * 16 + lr] = (bf16_t)o[cf][rr];
  }
  __syncthreads();
  if (c == 0) {
    float* Op = Opart + (size_t)(h * 1024 + qsi) * 1024;
    float* mlp = mlpart + (size_t)(h * 1024 + qsi) * 32;
#pragma unroll
    for (int rr = 0; rr < 4; ++rr) {
      const int row = lg * 4 + rr;
      float M = m[rr];
      float mv[3];
#pragma unroll
      for (int cc = 0; cc < 3; ++cc) {
        mv[cc] = ml_lds[cc][row][0];
        M = fmaxf(M, mv[cc]);
      }
      float f0 = __expf(m[rr] - M);
      float Lsum = ssum[rr] * f0;
      float fc[3];
#pragma unroll
      for (int cc = 0; cc < 3; ++cc) {
        fc[cc] = __expf(mv[cc] - M);
        Lsum += ml_lds[cc][row][1] * fc[cc];
      }
      if (lr == 0) { mlp[row * 2] = M; mlp[row * 2 + 1] = Lsum; }
#pragma unroll
      for (int cf = 0; cf < 4; ++cf) {
        float val = o[cf][rr] * f0;
#pragma unroll
        for (int cc = 0; cc < 3; ++cc)
          val += (float)od_lds[cc][row][cf * 16 + lr] * fc[cc];
        Op[row * 64 + cf * 16 + lr] = val;  // unnormalized
      }
    }
  }
}

// ---- kernel 4: merge the two split-K halves ----
__global__ __launch_bounds__(64) void combine_kernel(
    const float* __restrict__ Opart, const float* __restrict__ mlpart,
    float* __restrict__ out) {
  const int b = blockIdx.x;  // 0..1023 == qsi
  const int batch = b & 3, strip = (b >> 2) & 3, qt = 63 - (b >> 4);
  const int l = threadIdx.x;
  const int row = l >> 2, c0 = (l & 3) * 16;
  const float* ml0 = mlpart + ((size_t)(0 * 1024 + b) * 16 + row) * 2;
  const float* ml1 = mlpart + ((size_t)(1 * 1024 + b) * 16 + row) * 2;
  float m0 = ml0[0], l0 = ml0[1], m1 = ml1[0], l1 = ml1[1];
  float M = fmaxf(m0, m1);
  float f0 = __expf(m0 - M), f1 = __expf(m1 - M);
  float inv = 1.f / (l0 * f0 + l1 * f1);
  const float* O0 = Opart + (size_t)(0 * 1024 + b) * 1024 + row * 64 + c0;
  const float* O1 = Opart + (size_t)(1 * 1024 + b) * 1024 + row * 64 + c0;
  float* dst = out + ((size_t)batch * S_ + qt * 64 + strip * 16 + row) * L_ + c0;
#pragma unroll
  for (int j = 0; j < 4; ++j) {
    float4 a = reinterpret_cast<const float4*>(O0)[j];
    float4 bb = reinterpret_cast<const float4*>(O1)[j];
    float4 v;
    v.x = (a.x * f0 + bb.x * f1) * inv;
    v.y = (a.y * f0 + bb.y * f1) * inv;
    v.z = (a.z * f0 + bb.z * f1) * inv;
    v.w = (a.w * f0 + bb.w * f1) * inv;
    reinterpret_cast<float4*>(dst)[j] = v;
  }
}

extern "C" void kernel_launch(void* const* d_in, const int* in_sizes, int n_in,
                              void* d_out, int out_size, void* d_ws, size_t ws_size,
                              hipStream_t stream) {
  (void)in_sizes; (void)n_in; (void)out_size; (void)ws_size;
  const float* x  = (const float*)d_in[0];
  const float* Wq = (const float*)d_in[1];
  const float* Wk = (const float*)d_in[2];
  const float* Wv = (const float*)d_in[3];
  const float* bq = (const float*)d_in[4];
  const float* bk = (const float*)d_in[5];
  const float* bv = (const float*)d_in[6];
  // d_in[7] = mask; tril(ones) by construction -> causal hard-coded.
  float* out = (float*)d_out;

  char* ws = (char*)d_ws;
  bf16_t* Qf  = (bf16_t*)(ws + 0);                        // 2 MiB
  bf16_t* Kf  = (bf16_t*)(ws + (size_t)2 * 1024 * 1024);  // 2 MiB
  bf16_t* Vf  = (bf16_t*)(ws + (size_t)4 * 1024 * 1024);  // 2 MiB
  bf16_t* Wf  = (bf16_t*)(ws + (size_t)6 * 1024 * 1024);  // 384 KiB
  float* Opart = (float*)(ws + (size_t)7 * 1024 * 1024);  // 8 MiB
  float* mlpart = (float*)(ws + (size_t)15 * 1024 * 1024); // 256 KiB

  hipLaunchKernelGGL(prep_w_kernel, dim3(192), dim3(256), 0, stream, Wq, Wk, Wv, Wf);
  hipLaunchKernelGGL(qkv_proj_kernel, dim3(16384 / 64), dim3(512), 0, stream,
                     x, Wf, bq, bk, bv, Qf, Kf, Vf);
  hipLaunchKernelGGL(attn_kernel, dim3(2048), dim3(256), 0, stream,
                     Qf, Kf, Vf, Opart, mlpart);
  hipLaunchKernelGGL(combine_kernel, dim3(1024), dim3(64), 0, stream,
                     Opart, mlpart, out);
}

// Round 10
// 61.477 us; speedup vs baseline: 1.0496x; 1.0496x over previous
//
#include <hip/hip_runtime.h>
#include <hip/hip_bf16.h>
#include <cstdint>

typedef __bf16 bf16_t;
typedef __bf16 bf16x8 __attribute__((ext_vector_type(8)));
typedef float f32x4 __attribute__((ext_vector_type(4)));

#define B_ 4
#define S_ 4096
#define E_ 1024
#define L_ 64

__device__ __forceinline__ f32x4 mfma16(bf16x8 a, bf16x8 b, f32x4 c) {
  return __builtin_amdgcn_mfma_f32_16x16x32_bf16(a, b, c, 0, 0, 0);
}

// DPP rotate-reduce within 16-lane rows (VALU, no LDS traffic).
template <int CTRL>
__device__ __forceinline__ float dpp_max_step(float x) {
  int t = __builtin_amdgcn_update_dpp(0, __float_as_int(x), CTRL, 0xF, 0xF, true);
  return fmaxf(x, __int_as_float(t));
}
template <int CTRL>
__device__ __forceinline__ float dpp_add_step(float x) {
  int t = __builtin_amdgcn_update_dpp(0, __float_as_int(x), CTRL, 0xF, 0xF, true);
  return x + __int_as_float(t);
}
__device__ __forceinline__ float dpp_reduce_max16(float x) {
  x = dpp_max_step<0x121>(x);
  x = dpp_max_step<0x122>(x);
  x = dpp_max_step<0x124>(x);
  x = dpp_max_step<0x128>(x);
  return x;
}
__device__ __forceinline__ float dpp_reduce_add16(float x) {
  x = dpp_add_step<0x121>(x);
  x = dpp_add_step<0x122>(x);
  x = dpp_add_step<0x124>(x);
  x = dpp_add_step<0x128>(x);
  return x;
}

// Fragment-tile layout: tile = (16 rows x 32 k); flat ((tile)*64 + lane)*8,
// lane = lg*16+lr holds M[t_row*16+lr][t_k*32+lg*8..+8]. Wave fragment load =
// base + l*16B -> one coalesced 1KB access.

// ---- kernel 1: W [E][64] -> Wf fragment tiles (nt 0..11, kt 0..31) ----
__global__ void prep_w_kernel(const float* __restrict__ Wq, const float* __restrict__ Wk,
                              const float* __restrict__ Wv, bf16_t* __restrict__ Wf) {
  int n = blockIdx.x;  // 0..191 output col (W^T row)
  const float* W = (n < 64) ? Wq : (n < 128 ? Wk : Wv);
  int col = n & 63;
  int nt = n >> 4, lr = n & 15;
  for (int k = threadIdx.x; k < E_; k += blockDim.x) {
    int kt = k >> 5, lg = (k >> 3) & 3, e = k & 7;
    Wf[((size_t)((nt * 32 + kt) * 64 + lg * 16 + lr) << 3) + e] = (bf16_t)W[(size_t)k * L_ + col];
  }
}

// ---- kernel 2: QKV projection v4. BM=32, 66KB LDS -> 2 blocks/CU so one
// block's compute hides the sibling's staging. One-shot stage (1 barrier),
// barrier-free unrolled compute, LDS-staged coalesced fragment epilogue. ----
__global__ __launch_bounds__(512) void qkv_proj_kernel(
    const float* __restrict__ x, const bf16_t* __restrict__ Wf,
    const float* __restrict__ bq, const float* __restrict__ bk, const float* __restrict__ bv,
    bf16_t* __restrict__ Qf, bf16_t* __restrict__ Kf, bf16_t* __restrict__ Vf) {
  __shared__ __align__(16) char smem[32 * 1032 * 2];  // 66048 B -> 2 blocks/CU
  bf16_t* xls = reinterpret_cast<bf16_t*>(smem);      // [32][1032] (16B-odd stride)
  bf16_t* stc = reinterpret_cast<bf16_t*>(smem);      // epilogue alias [32][200]

  const int tid = threadIdx.x;
  const int w = tid >> 6, l = tid & 63;
  const int lr = l & 15, lg = l >> 4;
  const int rowgrp = w & 1, colgrp = w >> 1;  // 2 x 4 waves
  const int m0 = blockIdx.x * 32;

  // ---- stage x-slice (32x1024 f32 -> bf16 LDS), wave-contiguous loads ----
  {
    const float* xb = x + (size_t)m0 * E_;
#pragma unroll
    for (int i = 0; i < 8; ++i) {
      const int base = (i * 512 + tid) * 8;  // flat float idx, 0..32767
      float4 u0 = *reinterpret_cast<const float4*>(xb + base);
      float4 u1 = *reinterpret_cast<const float4*>(xb + base + 4);
      bf16x8 pk;
      pk[0] = (bf16_t)u0.x; pk[1] = (bf16_t)u0.y; pk[2] = (bf16_t)u0.z; pk[3] = (bf16_t)u0.w;
      pk[4] = (bf16_t)u1.x; pk[5] = (bf16_t)u1.y; pk[6] = (bf16_t)u1.z; pk[7] = (bf16_t)u1.w;
      const int row = base >> 10, col = base & 1023;
      *reinterpret_cast<bf16x8*>(xls + row * 1032 + col) = pk;
    }
  }
  __syncthreads();

  // ---- compute: wave = rows [rowgrp*16,+16) x cols [colgrp*48,+48) ----
  f32x4 acc[3];
#pragma unroll
  for (int t = 0; t < 3; ++t) acc[t] = f32x4{0.f, 0.f, 0.f, 0.f};

  const bf16_t* xa = xls + (size_t)(rowgrp * 16 + lr) * 1032 + lg * 8;
#pragma unroll
  for (int kt = 0; kt < 32; ++kt) {
    bf16x8 a = *reinterpret_cast<const bf16x8*>(xa + kt * 32);
#pragma unroll
    for (int t = 0; t < 3; ++t) {
      const int nt = colgrp * 3 + t;
      bf16x8 b = *reinterpret_cast<const bf16x8*>(Wf + (((size_t)(nt * 32 + kt) * 64 + l) << 3));
      acc[t] = mfma16(a, b, acc[t]);
    }
  }
  __syncthreads();  // xls reads retired; smem reused as stc

  // ---- C (+bias) -> stc[32][200] bf16 ----
#pragma unroll
  for (int t = 0; t < 3; ++t) {
    const int colb = colgrp * 48 + t * 16;  // 16-tile never straddles a matrix
    const int col = colb + lr;
    const int mat = colb >> 6;
    const float* bias = (mat == 0) ? bq : (mat == 1 ? bk : bv);
    const float bb = bias[col & 63];
#pragma unroll
    for (int r = 0; r < 4; ++r) {
      const int row = rowgrp * 16 + lg * 4 + r;
      stc[row * 200 + col] = (bf16_t)(acc[t][r] + bb);
    }
  }
  __syncthreads();

  // ---- fragment-layout coalesced 16B global stores ----
  if (tid < 256) {
    // Q and K: (rt 0..1, ktq 0..1, lane 0..63)
    const int rt = tid >> 7, ktq = (tid >> 6) & 1, lane = tid & 63;
    const int lgw = lane >> 4, lrw = lane & 15;
    const int rtg = (m0 >> 4) + rt;
    bf16x8 qv = *reinterpret_cast<const bf16x8*>(stc + (rt * 16 + lrw) * 200 + ktq * 32 + lgw * 8);
    *reinterpret_cast<bf16x8*>(Qf + (((size_t)(rtg * 2 + ktq) * 64 + lane) << 3)) = qv;
    bf16x8 kv = *reinterpret_cast<const bf16x8*>(stc + (rt * 16 + lrw) * 200 + 64 + ktq * 32 + lgw * 8);
    *reinterpret_cast<bf16x8*>(Kf + (((size_t)(rtg * 2 + ktq) * 64 + lane) << 3)) = kv;
  } else {
    // V: (vt 0..3, lane 0..63); one 32-row s-tile per block
    const int t2 = tid - 256;
    const int vt = t2 >> 6, lane = t2 & 63;
    const int lgv = lane >> 4, lrv = lane & 15;
    const int colv = vt * 16 + lrv;
    bf16x8 vv;
#pragma unroll
    for (int e = 0; e < 8; ++e)
      vv[e] = stc[(lgv * 8 + e) * 200 + 128 + colv];
    const int batch = m0 >> 12;
    const int stg = (m0 & (S_ - 1)) >> 5;
    *reinterpret_cast<bf16x8*>(Vf + ((size_t)batch << 18) + (((size_t)(stg * 4 + vt) * 64 + lane) << 3)) = vv;
  }
}

// ---- kernel 3: causal flash attention, split-K x8 (unchanged from R7/R8). ----
__global__ __launch_bounds__(256) void attn_kernel(
    const bf16_t* __restrict__ Qf, const bf16_t* __restrict__ Kf,
    const bf16_t* __restrict__ Vf, float* __restrict__ Opart, float* __restrict__ mlpart) {
  __shared__ __align__(16) bf16_t p_lds[4][16 * 72];  // 9 KiB P staging
  __shared__ bf16_t od_lds[3][16][68];                 // 6.4 KiB partial O (bf16)
  __shared__ float ml_lds[3][16][2];

  const int c = threadIdx.x >> 6, l = threadIdx.x & 63;
  const int lr = l & 15, lg = l >> 4;
  const int u = blockIdx.x;
  const int batch = u & 3;
  const int strip = (u >> 2) & 3;
  const int h = (u >> 4) & 1;
  const int qt = 63 - (u >> 5);
  const int qsi = ((u >> 5) << 4) | (u & 15);  // 0..1023 q-strip id
  const int qrow = qt * 64 + strip * 16;       // batch-local
  const size_t qbase = (size_t)batch * S_ + qrow;
  bf16_t* pw = p_lds[c];

  const int rtq = batch * 256 + qt * 4 + strip;  // global 16-row tile of Q
  bf16x8 qa0 = *reinterpret_cast<const bf16x8*>(Qf + (((size_t)(rtq * 2) * 64 + l) << 3));
  bf16x8 qa1 = *reinterpret_cast<const bf16x8*>(Qf + (((size_t)(rtq * 2 + 1) * 64 + l) << 3));
  const bf16_t* Vb = Vf + ((size_t)batch << 18);

  f32x4 o[4];
  float m[4], ssum[4];
#pragma unroll
  for (int rr = 0; rr < 4; ++rr) { o[rr] = f32x4{0.f, 0.f, 0.f, 0.f}; m[rr] = -1e30f; ssum[rr] = 0.f; }

  for (int kt = 2 * c + h; kt <= qt; kt += 8) {
    const int t0 = kt * 64;
    f32x4 st[4];
#pragma unroll
    for (int cf = 0; cf < 4; ++cf) st[cf] = f32x4{0.f, 0.f, 0.f, 0.f};
#pragma unroll
    for (int cf = 0; cf < 4; ++cf) {
      const int rtk = batch * 256 + kt * 4 + cf;
      bf16x8 b0 = *reinterpret_cast<const bf16x8*>(Kf + (((size_t)(rtk * 2) * 64 + l) << 3));
      bf16x8 b1 = *reinterpret_cast<const bf16x8*>(Kf + (((size_t)(rtk * 2 + 1) * 64 + l) << 3));
      st[cf] = mfma16(qa0, b0, st[cf]);
      st[cf] = mfma16(qa1, b1, st[cf]);
    }
    const bool diag = (kt == qt);
    float p[4][4];  // [cf][reg]
#pragma unroll
    for (int rr = 0; rr < 4; ++rr) {
      const int qg = qrow + lg * 4 + rr;
      float rowmax = -1e30f;
#pragma unroll
      for (int cf = 0; cf < 4; ++cf) {
        float s = st[cf][rr] * 0.125f;  // 1/sqrt(64)
        if (diag && (t0 + cf * 16 + lr) > qg) s = -1e30f;
        p[cf][rr] = s;
        rowmax = fmaxf(rowmax, s);
      }
      rowmax = dpp_reduce_max16(rowmax);
      float mnew = fmaxf(m[rr], rowmax);
      float scale = __expf(m[rr] - mnew);
      float rs = 0.f;
#pragma unroll
      for (int cf = 0; cf < 4; ++cf) {
        float e = __expf(p[cf][rr] - mnew);
        p[cf][rr] = e;
        rs += e;
      }
      rs = dpp_reduce_add16(rs);
      ssum[rr] = ssum[rr] * scale + rs;
#pragma unroll
      for (int cf = 0; cf < 4; ++cf) o[cf][rr] *= scale;
      m[rr] = mnew;
    }
    // P (C-layout) -> LDS -> A-layout fragments (wave-private, no barrier)
#pragma unroll
    for (int rr = 0; rr < 4; ++rr)
#pragma unroll
      for (int cf = 0; cf < 4; ++cf)
        pw[(lg * 4 + rr) * 72 + cf * 16 + lr] = (bf16_t)p[cf][rr];
    bf16x8 pa0 = *reinterpret_cast<const bf16x8*>(pw + lr * 72 + lg * 8);
    bf16x8 pa1 = *reinterpret_cast<const bf16x8*>(pw + lr * 72 + 32 + lg * 8);
    const int st0 = kt * 2;
#pragma unroll
    for (int cf = 0; cf < 4; ++cf) {
      bf16x8 v0 = *reinterpret_cast<const bf16x8*>(Vb + (((size_t)((st0 * 4 + cf) * 64 + l)) << 3));
      bf16x8 v1 = *reinterpret_cast<const bf16x8*>(Vb + (((size_t)(((st0 + 1) * 4 + cf) * 64 + l)) << 3));
      o[cf] = mfma16(pa0, v0, o[cf]);
      o[cf] = mfma16(pa1, v1, o[cf]);
    }
  }

  // chunks c=1..3 export to LDS; c=0 merges, writes unnormalized partial.
  if (c > 0) {
    if (lr == 0) {
#pragma unroll
      for (int rr = 0; rr < 4; ++rr) {
        ml_lds[c - 1][lg * 4 + rr][0] = m[rr];
        ml_lds[c - 1][lg * 4 + rr][1] = ssum[rr];
      }
    }
#pragma unroll
    for (int cf = 0; cf < 4; ++cf)
#pragma unroll
      for (int rr = 0; rr < 4; ++rr)
        od_lds[c - 1][lg * 4 + rr][cf * 16 + lr] = (bf16_t)o[cf][rr];
  }
  __syncthreads();
  if (c == 0) {
    float* Op = Opart + (size_t)(h * 1024 + qsi) * 1024;
    float* mlp = mlpart + (size_t)(h * 1024 + qsi) * 32;
#pragma unroll
    for (int rr = 0; rr < 4; ++rr) {
      const int row = lg * 4 + rr;
      float M = m[rr];
      float mv[3];
#pragma unroll
      for (int cc = 0; cc < 3; ++cc) {
        mv[cc] = ml_lds[cc][row][0];
        M = fmaxf(M, mv[cc]);
      }
      float f0 = __expf(m[rr] - M);
      float Lsum = ssum[rr] * f0;
      float fc[3];
#pragma unroll
      for (int cc = 0; cc < 3; ++cc) {
        fc[cc] = __expf(mv[cc] - M);
        Lsum += ml_lds[cc][row][1] * fc[cc];
      }
      if (lr == 0) { mlp[row * 2] = M; mlp[row * 2 + 1] = Lsum; }
#pragma unroll
      for (int cf = 0; cf < 4; ++cf) {
        float val = o[cf][rr] * f0;
#pragma unroll
        for (int cc = 0; cc < 3; ++cc)
          val += (float)od_lds[cc][row][cf * 16 + lr] * fc[cc];
        Op[row * 64 + cf * 16 + lr] = val;  // unnormalized
      }
    }
  }
}

// ---- kernel 4: merge the two split-K halves ----
__global__ __launch_bounds__(64) void combine_kernel(
    const float* __restrict__ Opart, const float* __restrict__ mlpart,
    float* __restrict__ out) {
  const int b = blockIdx.x;  // 0..1023 == qsi
  const int batch = b & 3, strip = (b >> 2) & 3, qt = 63 - (b >> 4);
  const int l = threadIdx.x;
  const int row = l >> 2, c0 = (l & 3) * 16;
  const float* ml0 = mlpart + ((size_t)(0 * 1024 + b) * 16 + row) * 2;
  const float* ml1 = mlpart + ((size_t)(1 * 1024 + b) * 16 + row) * 2;
  float m0 = ml0[0], l0 = ml0[1], m1 = ml1[0], l1 = ml1[1];
  float M = fmaxf(m0, m1);
  float f0 = __expf(m0 - M), f1 = __expf(m1 - M);
  float inv = 1.f / (l0 * f0 + l1 * f1);
  const float* O0 = Opart + (size_t)(0 * 1024 + b) * 1024 + row * 64 + c0;
  const float* O1 = Opart + (size_t)(1 * 1024 + b) * 1024 + row * 64 + c0;
  float* dst = out + ((size_t)batch * S_ + qt * 64 + strip * 16 + row) * L_ + c0;
#pragma unroll
  for (int j = 0; j < 4; ++j) {
    float4 a = reinterpret_cast<const float4*>(O0)[j];
    float4 bb = reinterpret_cast<const float4*>(O1)[j];
    float4 v;
    v.x = (a.x * f0 + bb.x * f1) * inv;
    v.y = (a.y * f0 + bb.y * f1) * inv;
    v.z = (a.z * f0 + bb.z * f1) * inv;
    v.w = (a.w * f0 + bb.w * f1) * inv;
    reinterpret_cast<float4*>(dst)[j] = v;
  }
}

extern "C" void kernel_launch(void* const* d_in, const int* in_sizes, int n_in,
                              void* d_out, int out_size, void* d_ws, size_t ws_size,
                              hipStream_t stream) {
  (void)in_sizes; (void)n_in; (void)out_size; (void)ws_size;
  const float* x  = (const float*)d_in[0];
  const float* Wq = (const float*)d_in[1];
  const float* Wk = (const float*)d_in[2];
  const float* Wv = (const float*)d_in[3];
  const float* bq = (const float*)d_in[4];
  const float* bk = (const float*)d_in[5];
  const float* bv = (const float*)d_in[6];
  // d_in[7] = mask; tril(ones) by construction -> causal hard-coded.
  float* out = (float*)d_out;

  char* ws = (char*)d_ws;
  bf16_t* Qf  = (bf16_t*)(ws + 0);                        // 2 MiB
  bf16_t* Kf  = (bf16_t*)(ws + (size_t)2 * 1024 * 1024);  // 2 MiB
  bf16_t* Vf  = (bf16_t*)(ws + (size_t)4 * 1024 * 1024);  // 2 MiB
  bf16_t* Wf  = (bf16_t*)(ws + (size_t)6 * 1024 * 1024);  // 384 KiB
  float* Opart = (float*)(ws + (size_t)7 * 1024 * 1024);  // 8 MiB
  float* mlpart = (float*)(ws + (size_t)15 * 1024 * 1024); // 256 KiB

  hipLaunchKernelGGL(prep_w_kernel, dim3(192), dim3(256), 0, stream, Wq, Wk, Wv, Wf);
  hipLaunchKernelGGL(qkv_proj_kernel, dim3(16384 / 32), dim3(512), 0, stream,
                     x, Wf, bq, bk, bv, Qf, Kf, Vf);
  hipLaunchKernelGGL(attn_kernel, dim3(2048), dim3(256), 0, stream,
                     Qf, Kf, Vf, Opart, mlpart);
  hipLaunchKernelGGL(combine_kernel, dim3(1024), dim3(64), 0, stream,
                     Opart, mlpart, out);
}